// Round 19
// baseline (294.327 us; speedup 1.0000x reference)
//
#include <hip/hip_runtime.h>

#define EMBED 512
#define LATENT 32
#define SEQ 2048
#define MTOT 4096
#define VOCAB 32000

typedef float f32x4 __attribute__((ext_vector_type(4)));
typedef short s16x8 __attribute__((ext_vector_type(8)));

__device__ __forceinline__ unsigned short f2bf(float f) {
  unsigned u = __float_as_uint(f);
  u += 0x7FFFu + ((u >> 16) & 1u);
  return (unsigned short)(u >> 16);
}

__device__ __forceinline__ void mfma16x16x32(f32x4& d, s16x8 a, s16x8 b) {
  asm("v_mfma_f32_16x16x32_bf16 %0, %1, %2, %0" : "+v"(d) : "v"(a), "v"(b));
}

__device__ __forceinline__ void gload16(const void* g, void* l) {
  __builtin_amdgcn_global_load_lds(
      (const __attribute__((address_space(1))) void*)g,
      (__attribute__((address_space(3))) void*)l, 16, 0, 0);
}

// ---------------- downscale: lat = in @ Wd + bd (R17 keeper) ----------------
__global__ __launch_bounds__(256) void k_downscale(
    const float* __restrict__ Q, const float* __restrict__ K,
    const float* __restrict__ V, const float* __restrict__ X,
    const float* __restrict__ Wd, const float* __restrict__ bd,
    float* __restrict__ latq, float* __restrict__ latk,
    float* __restrict__ latv, float* __restrict__ latx) {
  __shared__ float wdT[32][516];
  const float* in; float* out;
  switch (blockIdx.y) {
    case 0: in = Q; out = latq; break;
    case 1: in = K; out = latk; break;
    case 2: in = V; out = latv; break;
    default: in = X; out = latx; break;
  }
  int t = threadIdx.x;
#pragma unroll
  for (int j = 0; j < 16; ++j) {
    int q = t * 64 + j * 4;  // flat index into Wd [512][32]
    f32x4 v = *(const f32x4*)(Wd + q);
    int k = q >> 5, c = q & 31;
    wdT[c + 0][k] = v.x;
    wdT[c + 1][k] = v.y;
    wdT[c + 2][k] = v.z;
    wdT[c + 3][k] = v.w;
  }
  __syncthreads();
  int r = t >> 5, c = t & 31;
#pragma unroll 1
  for (int p = 0; p < 4; ++p) {
    int row = blockIdx.x * 32 + p * 8 + r;
    const float* rowp = in + (size_t)row * EMBED;
    float acc = 0.f;
#pragma unroll 8
    for (int k = 0; k < 512; k += 4) {
      f32x4 iv = *(const f32x4*)(rowp + k);  // broadcast within half-wave
      f32x4 wv = *(const f32x4*)&wdT[c][k];
      acc += iv.x * wv.x + iv.y * wv.y + iv.z * wv.z + iv.w * wv.w;
    }
    out[(size_t)row * 32 + c] = acc + bd[c];
  }
}

// ---------------- causal attention: R16 exact (keeper) ----------------------
__global__ __launch_bounds__(256) void k_attn(
    const float* __restrict__ lq, const float* __restrict__ lk,
    const float* __restrict__ lv, float* __restrict__ ctx) {
  __shared__ char kvbuf[4][16384];  // per-wave: K 8KB | V 8KB
  int lane = threadIdx.x & 63;
  int lw = threadIdx.x >> 6;
  int bl = blockIdx.x;  // 0..1023
  int qg;
  switch (lw) {
    case 0: qg = bl; break;
    case 1: qg = 2047 - bl; break;
    case 2: qg = 2048 + bl; break;
    default: qg = 4095 - bl; break;
  }
  int batch = qg >> 11;
  int qi = qg & 2047;
  const float* qp = lq + (size_t)qg * 32;
  f32x4 q4[8], ca[8];
#pragma unroll
  for (int d = 0; d < 8; ++d) {
    q4[d] = *(const f32x4*)(qp + d * 4);
    ca[d] = f32x4{0.f, 0.f, 0.f, 0.f};
  }
  const char* kbp = (const char*)(lk + (size_t)batch * SEQ * 32);
  const char* vbp = (const char*)(lv + (size_t)batch * SEQ * 32);
  char* kl = kvbuf[lw];
  char* vl = kvbuf[lw] + 8192;

  auto stage = [&](int j0) {
#pragma unroll
    for (int i = 0; i < 8; ++i) {
      int o = i * 1024 + lane * 16;
      int row = o >> 7;
      int sb = (((o >> 4) & 7) ^ (row & 7)) << 4;
      gload16(kbp + (size_t)(j0 + row) * 128 + sb, kl + o);
    }
#pragma unroll
    for (int i = 0; i < 8; ++i) {
      int o = i * 1024 + lane * 16;
      int row = o >> 7;
      int sb = (((o >> 4) & 7) ^ (row & 7)) << 4;
      gload16(vbp + (size_t)(j0 + row) * 128 + sb, vl + o);
    }
  };

  float m = -INFINITY, ssum = 0.f;
  const float scale = 0.17677669529663687f;  // 1/sqrt(32)
  int nChunk = (qi >> 6) + 1;

  stage(0);
  asm volatile("s_waitcnt vmcnt(0)" ::: "memory");

  for (int c = 0; c < nChunk; ++c) {
    f32x4 kr[8], vr[8];
#pragma unroll
    for (int d = 0; d < 8; ++d) {
      int sb = (d ^ (lane & 7)) << 4;
      kr[d] = *(const f32x4*)(kl + lane * 128 + sb);
      vr[d] = *(const f32x4*)(vl + lane * 128 + sb);
    }
    asm volatile("s_waitcnt lgkmcnt(0)" ::: "memory");
    __builtin_amdgcn_sched_barrier(0);
    if (c + 1 < nChunk) stage((c + 1) * 64);
    __builtin_amdgcn_sched_barrier(0);
    int j = c * 64 + lane;
    if (j <= qi) {
      f32x4 s4 = f32x4{0.f, 0.f, 0.f, 0.f};
#pragma unroll
      for (int d = 0; d < 8; ++d) s4 += q4[d] * kr[d];
      float s = (s4.x + s4.y + s4.z + s4.w) * scale;
      float mn = fmaxf(m, s);
      float f = __expf(m - mn);
      float p = __expf(s - mn);
      ssum = ssum * f + p;
#pragma unroll
      for (int d = 0; d < 8; ++d) ca[d] = ca[d] * f + p * vr[d];
      m = mn;
    }
    if (c + 1 < nChunk)
      asm volatile("s_waitcnt vmcnt(0)" ::: "memory");
  }

  float M = m;
#pragma unroll
  for (int off = 32; off > 0; off >>= 1) M = fmaxf(M, __shfl_xor(M, off, 64));
  float sc = (m == -INFINITY) ? 0.f : __expf(m - M);
  ssum *= sc;
#pragma unroll
  for (int off = 32; off > 0; off >>= 1) ssum += __shfl_xor(ssum, off, 64);
#pragma unroll
  for (int d = 0; d < 8; ++d) {
    ca[d] *= sc;
#pragma unroll
    for (int off = 32; off > 0; off >>= 1) {
      ca[d].x += __shfl_xor(ca[d].x, off, 64);
      ca[d].y += __shfl_xor(ca[d].y, off, 64);
      ca[d].z += __shfl_xor(ca[d].z, off, 64);
      ca[d].w += __shfl_xor(ca[d].w, off, 64);
    }
  }
  float inv = 1.f / ssum;
  float outv = 0.f;
#pragma unroll
  for (int d = 0; d < 32; ++d) {
    if (lane == d) outv = ca[d >> 2][d & 3];
  }
  if (lane < 32) ctx[(size_t)qg * 32 + lane] = outv * inv;
}

// -------- upscale + tile(ctx x16) + LayerNorm -> bf16 enc (R16 exact) -------
__global__ __launch_bounds__(512) void k_upln(
    const float* __restrict__ ctx, const float* __restrict__ latx,
    const float* __restrict__ Wu, const float* __restrict__ bu,
    const float* __restrict__ gamma, const float* __restrict__ beta,
    unsigned short* __restrict__ encb) {
  int r = blockIdx.x;
  int c = threadIdx.x;  // 0..511
  float acc = bu[c] + ctx[(size_t)r * 32 + (c & 31)];
  const float* lx = latx + (size_t)r * 32;
#pragma unroll
  for (int k = 0; k < 32; ++k) acc += lx[k] * Wu[k * EMBED + c];
  int lane = threadIdx.x & 63, w = threadIdx.x >> 6;
  float s1 = acc, s2 = acc * acc;
#pragma unroll
  for (int off = 32; off > 0; off >>= 1) {
    s1 += __shfl_xor(s1, off, 64);
    s2 += __shfl_xor(s2, off, 64);
  }
  __shared__ float r1[8], r2[8];
  if (lane == 0) { r1[w] = s1; r2[w] = s2; }
  __syncthreads();
  float t1 = 0.f, t2 = 0.f;
#pragma unroll
  for (int i = 0; i < 8; ++i) { t1 += r1[i]; t2 += r2[i]; }
  float mu = t1 * (1.f / 512.f);
  float var = t2 * (1.f / 512.f) - mu * mu;
  float rstd = rsqrtf(var + 1e-5f);
  float o = (acc - mu) * rstd * gamma[c] + beta[c];
  encb[(size_t)r * EMBED + c] = f2bf(o);
}

// -------- transpose + cast Wf -> WfT bf16 (R16 exact) -----------------------
__global__ __launch_bounds__(256) void k_transcast(
    const float* __restrict__ Wf, unsigned short* __restrict__ wfT) {
  __shared__ float tile[64][65];
  int n0 = blockIdx.x * 64;
  int k0 = blockIdx.y * 64;
  int t = threadIdx.x;
  int rr = t >> 4;         // 0..15
  int cq = (t & 15) << 2;  // 0..60
#pragma unroll
  for (int p = 0; p < 4; ++p) {
    int kr = p * 16 + rr;
    f32x4 v = *(const f32x4*)(Wf + (size_t)(k0 + kr) * VOCAB + n0 + cq);
    tile[kr][cq + 0] = v.x;
    tile[kr][cq + 1] = v.y;
    tile[kr][cq + 2] = v.z;
    tile[kr][cq + 3] = v.w;
  }
  __syncthreads();
#pragma unroll
  for (int p = 0; p < 4; ++p) {
    int nr = p * 16 + rr;
    ushort4 u;
    u.x = f2bf(tile[cq + 0][nr]);
    u.y = f2bf(tile[cq + 1][nr]);
    u.z = f2bf(tile[cq + 2][nr]);
    u.w = f2bf(tile[cq + 3][nr]);
    *(ushort4*)(wfT + (size_t)(n0 + nr) * EMBED + k0 + cq) = u;
  }
}

// ===== final GEMM: R16 structure + T4 counted vmcnt (3-slot ring) ===========
// R16 drains vmcnt(0)+barrier every tile: the staging queue empties at each
// barrier, exposing A's HBM first-touch latency (~900cy > the ~700cy
// ds_read+MFMA window). 3-slot ring + vmcnt(3): tile kt+2's loads stay in
// flight ACROSS the barrier (catalog T4, m218) — every load gets two full
// tile-times of cover. Slot (kt+2)%3 == (kt-1)%3, whose readers all passed
// the previous barrier (safe). 72KB LDS -> still 2 blocks/CU.
__global__ __launch_bounds__(512, 4) void k_gemm(
    const unsigned short* __restrict__ A,   // [4096][512] bf16
    const unsigned short* __restrict__ Bt,  // [32000][512] bf16
    const float* __restrict__ bias, float* __restrict__ C) {
  __shared__ char lds[3][24576];
  int tid = threadIdx.x;
  int lane = tid & 63, wave = tid >> 6;
  int wm = wave & 3, wn = wave >> 2;  // 4M x 2N wave grid
  int fr = lane & 15, fq = lane >> 4;
  int kswz = (fq ^ ((fr >> 1) & 3)) << 4;

  int id = blockIdx.x;
  int nid = (id & 7) * 500 + (id >> 3);
  int bm = nid & 15, bn = nid >> 4;
  int m0 = bm * 256, n0 = bn * 128;

  const char* Ab = (const char*)(A + (size_t)m0 * EMBED);
  const char* Bb = (const char*)(Bt + (size_t)n0 * EMBED);

  f32x4 acc[4][4];
#pragma unroll
  for (int i = 0; i < 4; ++i)
#pragma unroll
    for (int j = 0; j < 4; ++j) acc[i][j] = f32x4{0.f, 0.f, 0.f, 0.f};

  auto stage = [&](char* slot, int koff) {
#pragma unroll
    for (int i = 0; i < 2; ++i) {
      int o = i * 8192 + tid * 16;
      int row = o >> 6;
      int kb = (((o >> 4) & 3) ^ (((row) >> 1) & 3)) << 4;
      gload16(Ab + (size_t)row * 1024 + koff + kb, slot + o);
    }
    int o = tid * 16;
    int row = o >> 6;
    int kb = (((o >> 4) & 3) ^ ((row >> 1) & 3)) << 4;
    gload16(Bb + (size_t)row * 1024 + koff + kb, slot + 16384 + o);
  };

  // prologue: tiles 0,1 in flight; wait tile 0 only (tile 1 stays in flight)
  stage(&lds[0][0], 0);
  stage(&lds[1][0], 64);
  asm volatile("s_waitcnt vmcnt(3)" ::: "memory");
  __builtin_amdgcn_s_barrier();

  for (int kt = 0; kt < 16; ++kt) {
    const char* Ar = &lds[kt % 3][0];
    const char* Br = Ar + 16384;
    if (kt + 2 < 16) stage(&lds[(kt + 2) % 3][0], (kt + 2) * 64);
    s16x8 af[4];
#pragma unroll
    for (int mi = 0; mi < 4; ++mi) {
      int row = wm * 64 + mi * 16 + fr;
      af[mi] = *(const s16x8*)(Ar + row * 64 + kswz);
    }
    __builtin_amdgcn_s_setprio(1);
#pragma unroll
    for (int ni = 0; ni < 4; ++ni) {
      int row = wn * 64 + ni * 16 + fr;
      s16x8 bf = *(const s16x8*)(Br + row * 64 + kswz);
#pragma unroll
      for (int mi = 0; mi < 4; ++mi) mfma16x16x32(acc[mi][ni], af[mi], bf);
    }
    __builtin_amdgcn_s_setprio(0);
    // counted wait: tile kt+1 landed; tile kt+2's loads stay in flight
    if (kt <= 13) {
      asm volatile("s_waitcnt vmcnt(3)" ::: "memory");
    } else if (kt == 14) {
      asm volatile("s_waitcnt vmcnt(0)" ::: "memory");
    }
    __builtin_amdgcn_s_barrier();
  }
  // final barrier above also protects the epilogue's LDS reuse (slot 0)

  float* ep = (float*)&lds[0][0] + wave * 1088;  // 16 rows x 68 floats
  float bvv[4];
#pragma unroll
  for (int ni = 0; ni < 4; ++ni) bvv[ni] = bias[n0 + wn * 64 + ni * 16 + fr];
#pragma unroll
  for (int mi = 0; mi < 4; ++mi) {
#pragma unroll
    for (int ni = 0; ni < 4; ++ni)
#pragma unroll
      for (int r = 0; r < 4; ++r)
        ep[(fq * 4 + r) * 68 + ni * 16 + fr] = acc[mi][ni][r] + bvv[ni];
    __builtin_amdgcn_sched_barrier(0);
    asm volatile("s_waitcnt lgkmcnt(0)" ::: "memory");
    __builtin_amdgcn_sched_barrier(0);
#pragma unroll
    for (int p = 0; p < 4; ++p) {
      int row = p * 4 + fq;  // 0..15
      f32x4 v = *(const f32x4*)(ep + row * 68 + fr * 4);
      int m = m0 + wm * 64 + mi * 16 + row;
      __builtin_nontemporal_store(
          v, (f32x4*)(C + (size_t)m * VOCAB + n0 + wn * 64 + fr * 4));
    }
    __builtin_amdgcn_sched_barrier(0);
    asm volatile("s_waitcnt lgkmcnt(0)" ::: "memory");
    __builtin_amdgcn_sched_barrier(0);
  }
}

extern "C" void kernel_launch(void* const* d_in, const int* in_sizes, int n_in,
                              void* d_out, int out_size, void* d_ws,
                              size_t ws_size, hipStream_t stream) {
  (void)in_sizes; (void)n_in; (void)out_size; (void)ws_size;
  const float* Q = (const float*)d_in[0];
  const float* K = (const float*)d_in[1];
  const float* V = (const float*)d_in[2];
  const float* X = (const float*)d_in[3];
  const float* Wd = (const float*)d_in[4];
  const float* bd = (const float*)d_in[5];
  const float* Wu = (const float*)d_in[6];
  const float* bu = (const float*)d_in[7];
  const float* gamma = (const float*)d_in[8];
  const float* beta = (const float*)d_in[9];
  const float* Wf = (const float*)d_in[10];
  const float* bf = (const float*)d_in[11];
  float* out = (float*)d_out;
  char* ws = (char*)d_ws;
  float* latq = (float*)(ws + 0);
  float* latk = (float*)(ws + (1u << 19));
  float* latv = (float*)(ws + (2u << 19));
  float* latx = (float*)(ws + 3u * (1u << 19));
  float* ctx = (float*)(ws + (1u << 21));
  unsigned short* encb = (unsigned short*)(ws + (1u << 21) + (1u << 19));
  unsigned short* wfT =
      (unsigned short*)(ws + (1u << 21) + (1u << 19) + (1u << 22));

  k_downscale<<<dim3(128, 4), 256, 0, stream>>>(Q, K, V, X, Wd, bd, latq,
                                                latk, latv, latx);
  k_transcast<<<dim3(VOCAB / 64, EMBED / 64), 256, 0, stream>>>(Wf, wfT);
  k_attn<<<1024, 256, 0, stream>>>(latq, latk, latv, ctx);
  k_upln<<<MTOT, 512, 0, stream>>>(ctx, latx, Wu, bu, gamma, beta, encb);
  k_gemm<<<4000, 512, 0, stream>>>(encb, wfT, bf, out);
}

// Round 20
// 287.964 us; speedup vs baseline: 1.0221x; 1.0221x over previous
//
#include <hip/hip_runtime.h>

#define EMBED 512
#define LATENT 32
#define SEQ 2048
#define MTOT 4096
#define VOCAB 32000

typedef float f32x4 __attribute__((ext_vector_type(4)));
typedef short s16x8 __attribute__((ext_vector_type(8)));

__device__ __forceinline__ unsigned short f2bf(float f) {
  unsigned u = __float_as_uint(f);
  u += 0x7FFFu + ((u >> 16) & 1u);
  return (unsigned short)(u >> 16);
}

__device__ __forceinline__ void mfma16x16x32(f32x4& d, s16x8 a, s16x8 b) {
  asm("v_mfma_f32_16x16x32_bf16 %0, %1, %2, %0" : "+v"(d) : "v"(a), "v"(b));
}

__device__ __forceinline__ void gload16(const void* g, void* l) {
  __builtin_amdgcn_global_load_lds(
      (const __attribute__((address_space(1))) void*)g,
      (__attribute__((address_space(3))) void*)l, 16, 0, 0);
}

// ---------------- downscale: lat = in @ Wd + bd (R17 keeper) ----------------
__global__ __launch_bounds__(256) void k_downscale(
    const float* __restrict__ Q, const float* __restrict__ K,
    const float* __restrict__ V, const float* __restrict__ X,
    const float* __restrict__ Wd, const float* __restrict__ bd,
    float* __restrict__ latq, float* __restrict__ latk,
    float* __restrict__ latv, float* __restrict__ latx) {
  __shared__ float wdT[32][516];
  const float* in; float* out;
  switch (blockIdx.y) {
    case 0: in = Q; out = latq; break;
    case 1: in = K; out = latk; break;
    case 2: in = V; out = latv; break;
    default: in = X; out = latx; break;
  }
  int t = threadIdx.x;
#pragma unroll
  for (int j = 0; j < 16; ++j) {
    int q = t * 64 + j * 4;  // flat index into Wd [512][32]
    f32x4 v = *(const f32x4*)(Wd + q);
    int k = q >> 5, c = q & 31;
    wdT[c + 0][k] = v.x;
    wdT[c + 1][k] = v.y;
    wdT[c + 2][k] = v.z;
    wdT[c + 3][k] = v.w;
  }
  __syncthreads();
  int r = t >> 5, c = t & 31;
#pragma unroll 1
  for (int p = 0; p < 4; ++p) {
    int row = blockIdx.x * 32 + p * 8 + r;
    const float* rowp = in + (size_t)row * EMBED;
    float acc = 0.f;
#pragma unroll 8
    for (int k = 0; k < 512; k += 4) {
      f32x4 iv = *(const f32x4*)(rowp + k);  // broadcast within half-wave
      f32x4 wv = *(const f32x4*)&wdT[c][k];
      acc += iv.x * wv.x + iv.y * wv.y + iv.z * wv.z + iv.w * wv.w;
    }
    out[(size_t)row * 32 + c] = acc + bd[c];
  }
}

// ---------------- causal attention: R16 data path + Q-PAIRING ---------------
// Each wave handles queries {2pi, 2pi+1}: K/V staging (16 gloads/chunk) and
// the per-chunk vmcnt wait are SHARED across the pair (halved per query);
// the online-softmax compute is duplicated per query with R16-verbatim FP
// order (absmax must stay bit-identical). 512 blocks x 4 waves, long+short
// pair balancing. VGPR ~205, LDS 64KB -> 8 waves/CU (unchanged).
__global__ __launch_bounds__(256) void k_attn(
    const float* __restrict__ lq, const float* __restrict__ lk,
    const float* __restrict__ lv, float* __restrict__ ctx) {
  __shared__ char kvbuf[4][16384];  // per-wave: K 8KB | V 8KB
  int lane = threadIdx.x & 63;
  int lw = threadIdx.x >> 6;
  int bl = blockIdx.x;  // 0..511
  int pg;               // pair index 0..2047
  switch (lw) {
    case 0: pg = bl; break;
    case 1: pg = 1023 - bl; break;
    case 2: pg = 1024 + bl; break;
    default: pg = 2047 - bl; break;
  }
  int batch = pg >> 10;
  int pi = pg & 1023;
  int qia = 2 * pi, qib = 2 * pi + 1;      // within-batch query indices
  int rowa = batch * SEQ + qia;            // global rows
  const float* qpa = lq + (size_t)rowa * 32;
  f32x4 q4a[8], q4b[8], caa[8], cab[8];
#pragma unroll
  for (int d = 0; d < 8; ++d) {
    q4a[d] = *(const f32x4*)(qpa + d * 4);
    q4b[d] = *(const f32x4*)(qpa + 32 + d * 4);
    caa[d] = f32x4{0.f, 0.f, 0.f, 0.f};
    cab[d] = f32x4{0.f, 0.f, 0.f, 0.f};
  }
  const char* kbp = (const char*)(lk + (size_t)batch * SEQ * 32);
  const char* vbp = (const char*)(lv + (size_t)batch * SEQ * 32);
  char* kl = kvbuf[lw];
  char* vl = kvbuf[lw] + 8192;

  auto stage = [&](int j0) {
#pragma unroll
    for (int i = 0; i < 8; ++i) {
      int o = i * 1024 + lane * 16;
      int row = o >> 7;
      int sb = (((o >> 4) & 7) ^ (row & 7)) << 4;
      gload16(kbp + (size_t)(j0 + row) * 128 + sb, kl + o);
    }
#pragma unroll
    for (int i = 0; i < 8; ++i) {
      int o = i * 1024 + lane * 16;
      int row = o >> 7;
      int sb = (((o >> 4) & 7) ^ (row & 7)) << 4;
      gload16(vbp + (size_t)(j0 + row) * 128 + sb, vl + o);
    }
  };

  float ma = -INFINITY, ssa = 0.f;
  float mb = -INFINITY, ssb = 0.f;
  const float scale = 0.17677669529663687f;  // 1/sqrt(32)
  int nChunk = (qib >> 6) + 1;

  stage(0);
  asm volatile("s_waitcnt vmcnt(0)" ::: "memory");

  for (int c = 0; c < nChunk; ++c) {
    f32x4 kr[8], vr[8];
#pragma unroll
    for (int d = 0; d < 8; ++d) {
      int sb = (d ^ (lane & 7)) << 4;
      kr[d] = *(const f32x4*)(kl + lane * 128 + sb);
      vr[d] = *(const f32x4*)(vl + lane * 128 + sb);
    }
    asm volatile("s_waitcnt lgkmcnt(0)" ::: "memory");
    __builtin_amdgcn_sched_barrier(0);
    if (c + 1 < nChunk) stage((c + 1) * 64);
    __builtin_amdgcn_sched_barrier(0);
    int j = c * 64 + lane;
    if (j <= qia) {  // query a (R16-verbatim chain)
      f32x4 s4 = f32x4{0.f, 0.f, 0.f, 0.f};
#pragma unroll
      for (int d = 0; d < 8; ++d) s4 += q4a[d] * kr[d];
      float s = (s4.x + s4.y + s4.z + s4.w) * scale;
      float mn = fmaxf(ma, s);
      float f = __expf(ma - mn);
      float p = __expf(s - mn);
      ssa = ssa * f + p;
#pragma unroll
      for (int d = 0; d < 8; ++d) caa[d] = caa[d] * f + p * vr[d];
      ma = mn;
    }
    if (j <= qib) {  // query b
      f32x4 s4 = f32x4{0.f, 0.f, 0.f, 0.f};
#pragma unroll
      for (int d = 0; d < 8; ++d) s4 += q4b[d] * kr[d];
      float s = (s4.x + s4.y + s4.z + s4.w) * scale;
      float mn = fmaxf(mb, s);
      float f = __expf(mb - mn);
      float p = __expf(s - mn);
      ssb = ssb * f + p;
#pragma unroll
      for (int d = 0; d < 8; ++d) cab[d] = cab[d] * f + p * vr[d];
      mb = mn;
    }
    if (c + 1 < nChunk)
      asm volatile("s_waitcnt vmcnt(0)" ::: "memory");
  }

  // merge + write, query a
  {
    float M = ma;
#pragma unroll
    for (int off = 32; off > 0; off >>= 1) M = fmaxf(M, __shfl_xor(M, off, 64));
    float sc = (ma == -INFINITY) ? 0.f : __expf(ma - M);
    float ss = ssa * sc;
#pragma unroll
    for (int off = 32; off > 0; off >>= 1) ss += __shfl_xor(ss, off, 64);
#pragma unroll
    for (int d = 0; d < 8; ++d) {
      caa[d] *= sc;
#pragma unroll
      for (int off = 32; off > 0; off >>= 1) {
        caa[d].x += __shfl_xor(caa[d].x, off, 64);
        caa[d].y += __shfl_xor(caa[d].y, off, 64);
        caa[d].z += __shfl_xor(caa[d].z, off, 64);
        caa[d].w += __shfl_xor(caa[d].w, off, 64);
      }
    }
    float inv = 1.f / ss;
    float outv = 0.f;
#pragma unroll
    for (int d = 0; d < 32; ++d) {
      if (lane == d) outv = caa[d >> 2][d & 3];
    }
    if (lane < 32) ctx[(size_t)rowa * 32 + lane] = outv * inv;
  }
  // merge + write, query b
  {
    float M = mb;
#pragma unroll
    for (int off = 32; off > 0; off >>= 1) M = fmaxf(M, __shfl_xor(M, off, 64));
    float sc = (mb == -INFINITY) ? 0.f : __expf(mb - M);
    float ss = ssb * sc;
#pragma unroll
    for (int off = 32; off > 0; off >>= 1) ss += __shfl_xor(ss, off, 64);
#pragma unroll
    for (int d = 0; d < 8; ++d) {
      cab[d] *= sc;
#pragma unroll
      for (int off = 32; off > 0; off >>= 1) {
        cab[d].x += __shfl_xor(cab[d].x, off, 64);
        cab[d].y += __shfl_xor(cab[d].y, off, 64);
        cab[d].z += __shfl_xor(cab[d].z, off, 64);
        cab[d].w += __shfl_xor(cab[d].w, off, 64);
      }
    }
    float inv = 1.f / ss;
    float outv = 0.f;
#pragma unroll
    for (int d = 0; d < 32; ++d) {
      if (lane == d) outv = cab[d >> 2][d & 3];
    }
    if (lane < 32) ctx[(size_t)(rowa + 1) * 32 + lane] = outv * inv;
  }
}

// -------- upscale + tile(ctx x16) + LayerNorm -> bf16 enc (R16 exact) -------
__global__ __launch_bounds__(512) void k_upln(
    const float* __restrict__ ctx, const float* __restrict__ latx,
    const float* __restrict__ Wu, const float* __restrict__ bu,
    const float* __restrict__ gamma, const float* __restrict__ beta,
    unsigned short* __restrict__ encb) {
  int r = blockIdx.x;
  int c = threadIdx.x;  // 0..511
  float acc = bu[c] + ctx[(size_t)r * 32 + (c & 31)];
  const float* lx = latx + (size_t)r * 32;
#pragma unroll
  for (int k = 0; k < 32; ++k) acc += lx[k] * Wu[k * EMBED + c];
  int lane = threadIdx.x & 63, w = threadIdx.x >> 6;
  float s1 = acc, s2 = acc * acc;
#pragma unroll
  for (int off = 32; off > 0; off >>= 1) {
    s1 += __shfl_xor(s1, off, 64);
    s2 += __shfl_xor(s2, off, 64);
  }
  __shared__ float r1[8], r2[8];
  if (lane == 0) { r1[w] = s1; r2[w] = s2; }
  __syncthreads();
  float t1 = 0.f, t2 = 0.f;
#pragma unroll
  for (int i = 0; i < 8; ++i) { t1 += r1[i]; t2 += r2[i]; }
  float mu = t1 * (1.f / 512.f);
  float var = t2 * (1.f / 512.f) - mu * mu;
  float rstd = rsqrtf(var + 1e-5f);
  float o = (acc - mu) * rstd * gamma[c] + beta[c];
  encb[(size_t)r * EMBED + c] = f2bf(o);
}

// -------- transpose + cast Wf -> WfT bf16 (R16 exact) -----------------------
__global__ __launch_bounds__(256) void k_transcast(
    const float* __restrict__ Wf, unsigned short* __restrict__ wfT) {
  __shared__ float tile[64][65];
  int n0 = blockIdx.x * 64;
  int k0 = blockIdx.y * 64;
  int t = threadIdx.x;
  int rr = t >> 4;         // 0..15
  int cq = (t & 15) << 2;  // 0..60
#pragma unroll
  for (int p = 0; p < 4; ++p) {
    int kr = p * 16 + rr;
    f32x4 v = *(const f32x4*)(Wf + (size_t)(k0 + kr) * VOCAB + n0 + cq);
    tile[kr][cq + 0] = v.x;
    tile[kr][cq + 1] = v.y;
    tile[kr][cq + 2] = v.z;
    tile[kr][cq + 3] = v.w;
  }
  __syncthreads();
#pragma unroll
  for (int p = 0; p < 4; ++p) {
    int nr = p * 16 + rr;
    ushort4 u;
    u.x = f2bf(tile[cq + 0][nr]);
    u.y = f2bf(tile[cq + 1][nr]);
    u.z = f2bf(tile[cq + 2][nr]);
    u.w = f2bf(tile[cq + 3][nr]);
    *(ushort4*)(wfT + (size_t)(n0 + nr) * EMBED + k0 + cq) = u;
  }
}

// ===== final GEMM: R18/R16 byte-exact keeper (2-slot, NT epilogue) ==========
// R19's counted-vmcnt 3-slot ring was neutral (294.3 vs 291.8) -> reverted.
__global__ __launch_bounds__(512, 4) void k_gemm(
    const unsigned short* __restrict__ A,   // [4096][512] bf16
    const unsigned short* __restrict__ Bt,  // [32000][512] bf16
    const float* __restrict__ bias, float* __restrict__ C) {
  __shared__ char lds[2][24576];
  int tid = threadIdx.x;
  int lane = tid & 63, wave = tid >> 6;
  int wm = wave & 3, wn = wave >> 2;  // 4M x 2N wave grid
  int fr = lane & 15, fq = lane >> 4;
  int kswz = (fq ^ ((fr >> 1) & 3)) << 4;

  int id = blockIdx.x;
  int nid = (id & 7) * 500 + (id >> 3);
  int bm = nid & 15, bn = nid >> 4;
  int m0 = bm * 256, n0 = bn * 128;

  const char* Ab = (const char*)(A + (size_t)m0 * EMBED);
  const char* Bb = (const char*)(Bt + (size_t)n0 * EMBED);

  f32x4 acc[4][4];
#pragma unroll
  for (int i = 0; i < 4; ++i)
#pragma unroll
    for (int j = 0; j < 4; ++j) acc[i][j] = f32x4{0.f, 0.f, 0.f, 0.f};

  auto stage = [&](char* slot, int koff) {
#pragma unroll
    for (int i = 0; i < 2; ++i) {
      int o = i * 8192 + tid * 16;
      int row = o >> 6;
      int kb = (((o >> 4) & 3) ^ ((row >> 1) & 3)) << 4;
      gload16(Ab + (size_t)row * 1024 + koff + kb, slot + o);
    }
    int o = tid * 16;
    int row = o >> 6;
    int kb = (((o >> 4) & 3) ^ ((row >> 1) & 3)) << 4;
    gload16(Bb + (size_t)row * 1024 + koff + kb, slot + 16384 + o);
  };

  stage(&lds[0][0], 0);
  asm volatile("s_waitcnt vmcnt(0)" ::: "memory");
  __builtin_amdgcn_s_barrier();

  for (int kt = 0; kt < 16; ++kt) {
    const char* Ar = &lds[kt & 1][0];
    const char* Br = Ar + 16384;
    if (kt < 15) stage(&lds[(kt + 1) & 1][0], (kt + 1) * 64);
    s16x8 af[4];
#pragma unroll
    for (int mi = 0; mi < 4; ++mi) {
      int row = wm * 64 + mi * 16 + fr;
      af[mi] = *(const s16x8*)(Ar + row * 64 + kswz);
    }
    __builtin_amdgcn_s_setprio(1);
#pragma unroll
    for (int ni = 0; ni < 4; ++ni) {
      int row = wn * 64 + ni * 16 + fr;
      s16x8 bf = *(const s16x8*)(Br + row * 64 + kswz);
#pragma unroll
      for (int mi = 0; mi < 4; ++mi) mfma16x16x32(acc[mi][ni], af[mi], bf);
    }
    __builtin_amdgcn_s_setprio(0);
    asm volatile("s_waitcnt vmcnt(0)" ::: "memory");
    __builtin_amdgcn_s_barrier();
  }

  float* ep = (float*)&lds[0][0] + wave * 1088;  // 16 rows x 68 floats
  float bvv[4];
#pragma unroll
  for (int ni = 0; ni < 4; ++ni) bvv[ni] = bias[n0 + wn * 64 + ni * 16 + fr];
#pragma unroll
  for (int mi = 0; mi < 4; ++mi) {
#pragma unroll
    for (int ni = 0; ni < 4; ++ni)
#pragma unroll
      for (int r = 0; r < 4; ++r)
        ep[(fq * 4 + r) * 68 + ni * 16 + fr] = acc[mi][ni][r] + bvv[ni];
    __builtin_amdgcn_sched_barrier(0);
    asm volatile("s_waitcnt lgkmcnt(0)" ::: "memory");
    __builtin_amdgcn_sched_barrier(0);
#pragma unroll
    for (int p = 0; p < 4; ++p) {
      int row = p * 4 + fq;  // 0..15
      f32x4 v = *(const f32x4*)(ep + row * 68 + fr * 4);
      int m = m0 + wm * 64 + mi * 16 + row;
      __builtin_nontemporal_store(
          v, (f32x4*)(C + (size_t)m * VOCAB + n0 + wn * 64 + fr * 4));
    }
    __builtin_amdgcn_sched_barrier(0);
    asm volatile("s_waitcnt lgkmcnt(0)" ::: "memory");
    __builtin_amdgcn_sched_barrier(0);
  }
}

extern "C" void kernel_launch(void* const* d_in, const int* in_sizes, int n_in,
                              void* d_out, int out_size, void* d_ws,
                              size_t ws_size, hipStream_t stream) {
  (void)in_sizes; (void)n_in; (void)out_size; (void)ws_size;
  const float* Q = (const float*)d_in[0];
  const float* K = (const float*)d_in[1];
  const float* V = (const float*)d_in[2];
  const float* X = (const float*)d_in[3];
  const float* Wd = (const float*)d_in[4];
  const float* bd = (const float*)d_in[5];
  const float* Wu = (const float*)d_in[6];
  const float* bu = (const float*)d_in[7];
  const float* gamma = (const float*)d_in[8];
  const float* beta = (const float*)d_in[9];
  const float* Wf = (const float*)d_in[10];
  const float* bf = (const float*)d_in[11];
  float* out = (float*)d_out;
  char* ws = (char*)d_ws;
  float* latq = (float*)(ws + 0);
  float* latk = (float*)(ws + (1u << 19));
  float* latv = (float*)(ws + (2u << 19));
  float* latx = (float*)(ws + 3u * (1u << 19));
  float* ctx = (float*)(ws + (1u << 21));
  unsigned short* encb = (unsigned short*)(ws + (1u << 21) + (1u << 19));
  unsigned short* wfT =
      (unsigned short*)(ws + (1u << 21) + (1u << 19) + (1u << 22));

  k_downscale<<<dim3(128, 4), 256, 0, stream>>>(Q, K, V, X, Wd, bd, latq,
                                                latk, latv, latx);
  k_transcast<<<dim3(VOCAB / 64, EMBED / 64), 256, 0, stream>>>(Wf, wfT);
  k_attn<<<512, 256, 0, stream>>>(latq, latk, latv, ctx);
  k_upln<<<MTOT, 512, 0, stream>>>(ctx, latx, Wu, bu, gamma, beta, encb);
  k_gemm<<<4000, 512, 0, stream>>>(encb, wfT, bf, out);
}